// Round 11
// baseline (253.036 us; speedup 1.0000x reference)
//
#include <hip/hip_runtime.h>
#include <hip/hip_bf16.h>
#include <hip/hip_fp16.h>

#define NFEAT  128
#define HC     64
#define HEADS  4
#define NHID   16
#define NCLASS 40
#define NEG    0.2f
#define BN_EPS 1e-5f

#define BK_SH   9          // 512 nodes per bucket
#define CHUNK   8192       // edges per histogram/scatter workgroup
#define STAGE   12288      // LDS staging capacity in k_build

typedef _Float16 half8_t __attribute__((ext_vector_type(8)));
typedef _Float16 half4_t __attribute__((ext_vector_type(4)));
typedef float    f32x4_t __attribute__((ext_vector_type(4)));

__device__ __forceinline__ float leaky(float a) { return (a > 0.f) ? a : NEG * a; }

// ---------------------------------------------------------------------------
// Kernel 1 (MFMA): h1 = x @ W1 via v_mfma_f32_16x16x32_f16.
// ---------------------------------------------------------------------------
__global__ __launch_bounds__(256) void k_gemm1(
    const float* __restrict__ x, const float* __restrict__ W1,
    const float* __restrict__ att_s, const float* __restrict__ att_d,
    __half* __restrict__ h1, float* __restrict__ as1, float* __restrict__ ad1,
    int n)
{
    const int wave = threadIdx.x >> 6, lane = threadIdx.x & 63;
    const int quad = lane >> 4, l16 = lane & 15;

    half8_t bfrag[4][4];
    #pragma unroll
    for (int ks = 0; ks < 4; ++ks)
        #pragma unroll
        for (int ct = 0; ct < 4; ++ct)
            #pragma unroll
            for (int j = 0; j < 8; ++j)
                bfrag[ks][ct][j] =
                    (_Float16)W1[(ks * 32 + quad * 8 + j) * HC + ct * 16 + l16];

    float avs[4], avd[4];
    #pragma unroll
    for (int ct = 0; ct < 4; ++ct) {
        avs[ct] = att_s[ct * 16 + l16];
        avd[ct] = att_d[ct * 16 + l16];
    }

    const int nslab = (n + 15) >> 4;
    for (int slab = blockIdx.x * 4 + wave; slab < nslab; slab += gridDim.x * 4) {
        const int rowbase = slab * 16;
        const int arow = min(rowbase + l16, n - 1);
        const float* xp = x + (size_t)arow * NFEAT;

        f32x4_t acc[4] = {{0.f,0.f,0.f,0.f},{0.f,0.f,0.f,0.f},
                          {0.f,0.f,0.f,0.f},{0.f,0.f,0.f,0.f}};
        #pragma unroll
        for (int ks = 0; ks < 4; ++ks) {
            const float4 xa = *(const float4*)(xp + ks * 32 + quad * 8);
            const float4 xb = *(const float4*)(xp + ks * 32 + quad * 8 + 4);
            half8_t af;
            af[0] = (_Float16)xa.x; af[1] = (_Float16)xa.y;
            af[2] = (_Float16)xa.z; af[3] = (_Float16)xa.w;
            af[4] = (_Float16)xb.x; af[5] = (_Float16)xb.y;
            af[6] = (_Float16)xb.z; af[7] = (_Float16)xb.w;
            #pragma unroll
            for (int ct = 0; ct < 4; ++ct)
                acc[ct] = __builtin_amdgcn_mfma_f32_16x16x32_f16(
                    af, bfrag[ks][ct], acc[ct], 0, 0, 0);
        }

        #pragma unroll
        for (int reg = 0; reg < 4; ++reg) {
            const int row = rowbase + quad * 4 + reg;
            const bool valid = row < n;

            float4 ps, pd;
            ps.x = acc[0][reg] * avs[0]; pd.x = acc[0][reg] * avd[0];
            ps.y = acc[1][reg] * avs[1]; pd.y = acc[1][reg] * avd[1];
            ps.z = acc[2][reg] * avs[2]; pd.z = acc[2][reg] * avd[2];
            ps.w = acc[3][reg] * avs[3]; pd.w = acc[3][reg] * avd[3];
            #pragma unroll
            for (int off = 8; off >= 1; off >>= 1) {
                ps.x += __shfl_xor(ps.x, off, 64); pd.x += __shfl_xor(pd.x, off, 64);
                ps.y += __shfl_xor(ps.y, off, 64); pd.y += __shfl_xor(pd.y, off, 64);
                ps.z += __shfl_xor(ps.z, off, 64); pd.z += __shfl_xor(pd.z, off, 64);
                ps.w += __shfl_xor(ps.w, off, 64); pd.w += __shfl_xor(pd.w, off, 64);
            }
            if (valid) {
                #pragma unroll
                for (int ct = 0; ct < 4; ++ct)
                    h1[(size_t)row * HC + ct * 16 + l16] =
                        __float2half_rn(acc[ct][reg]);
                if (l16 == 0) {
                    *(float4*)(as1 + (size_t)row * HEADS) = ps;
                    *(float4*)(ad1 + (size_t)row * HEADS) = pd;
                }
            }
        }
    }
}

// ---------------------------------------------------------------------------
// Kernel gemm2 (MFMA): g = h2 @ W2 (64 -> 40) + layer-2 attention scores.
// g stored at STRIDE 40 (80 B rows) — no zero padding.
// ---------------------------------------------------------------------------
__global__ __launch_bounds__(256) void k_gemm2(
    const __half* __restrict__ h2, const float* __restrict__ W2,
    const float* __restrict__ ats2, const float* __restrict__ atd2,
    __half* __restrict__ g, float* __restrict__ as2, float* __restrict__ ad2,
    int n)
{
    const int wave = threadIdx.x >> 6, lane = threadIdx.x & 63;
    const int quad = lane >> 4, l16 = lane & 15;

    half8_t bfrag[2][3];
    #pragma unroll
    for (int ks = 0; ks < 2; ++ks)
        #pragma unroll
        for (int ct = 0; ct < 3; ++ct)
            #pragma unroll
            for (int j = 0; j < 8; ++j) {
                const int c = ct * 16 + l16;
                bfrag[ks][ct][j] = (c < NCLASS)
                    ? (_Float16)W2[(ks * 32 + quad * 8 + j) * NCLASS + c]
                    : (_Float16)0.f;
            }

    float avs[3], avd[3];
    #pragma unroll
    for (int ct = 0; ct < 3; ++ct) {
        const int c = ct * 16 + l16;
        avs[ct] = (c < NCLASS) ? ats2[c] : 0.f;
        avd[ct] = (c < NCLASS) ? atd2[c] : 0.f;
    }

    const int nslab = (n + 15) >> 4;
    for (int slab = blockIdx.x * 4 + wave; slab < nslab; slab += gridDim.x * 4) {
        const int rowbase = slab * 16;
        const int arow = min(rowbase + l16, n - 1);
        const __half* hp = h2 + (size_t)arow * HC;

        f32x4_t acc[3] = {{0.f,0.f,0.f,0.f},{0.f,0.f,0.f,0.f},
                          {0.f,0.f,0.f,0.f}};
        #pragma unroll
        for (int ks = 0; ks < 2; ++ks) {
            const half8_t af = *(const half8_t*)(hp + ks * 32 + quad * 8);
            #pragma unroll
            for (int ct = 0; ct < 3; ++ct)
                acc[ct] = __builtin_amdgcn_mfma_f32_16x16x32_f16(
                    af, bfrag[ks][ct], acc[ct], 0, 0, 0);
        }

        #pragma unroll
        for (int reg = 0; reg < 4; ++reg) {
            const int row = rowbase + quad * 4 + reg;
            const bool valid = row < n;

            float sv = acc[0][reg] * avs[0] + acc[1][reg] * avs[1]
                     + acc[2][reg] * avs[2];
            float dv = acc[0][reg] * avd[0] + acc[1][reg] * avd[1]
                     + acc[2][reg] * avd[2];
            #pragma unroll
            for (int off = 8; off >= 1; off >>= 1) {
                sv += __shfl_xor(sv, off, 64);
                dv += __shfl_xor(dv, off, 64);
            }
            if (valid) {
                #pragma unroll
                for (int ct = 0; ct < 3; ++ct) {
                    const int c = ct * 16 + l16;
                    if (c < NCLASS)
                        g[(size_t)row * NCLASS + c] = __float2half_rn(acc[ct][reg]);
                }
                if (l16 == 0) { as2[row] = sv; ad2[row] = dv; }
            }
        }
    }
}

// ---------------------------------------------------------------------------
// CSR build (locality-preserving, no global atomics, no memset)
// ---------------------------------------------------------------------------
__global__ __launch_bounds__(512) void k_hist(
    const int* __restrict__ edst, int* __restrict__ hist, int E, int nbk)
{
    __shared__ int lh[256];
    const int w = blockIdx.x, t = threadIdx.x;
    for (int i = t; i < nbk; i += 512) lh[i] = 0;
    __syncthreads();
    const int lo = w * CHUNK, hi = min(E, lo + CHUNK);
    for (int e = lo + 4 * t; e < hi; e += 4 * 512) {
        const int4 d4 = *(const int4*)(edst + e);
        atomicAdd(&lh[d4.x >> BK_SH], 1);
        atomicAdd(&lh[d4.y >> BK_SH], 1);
        atomicAdd(&lh[d4.z >> BK_SH], 1);
        atomicAdd(&lh[d4.w >> BK_SH], 1);
    }
    __syncthreads();
    for (int i = t; i < nbk; i += 512) hist[(size_t)w * nbk + i] = lh[i];
}

__global__ __launch_bounds__(256) void k_colscan(
    int* __restrict__ hist, int* __restrict__ colsum, int nbk, int nw)
{
    __shared__ int wred[4];
    const int b = blockIdx.x, t = threadIdx.x;
    const int lane = t & 63, w = t >> 6;
    const int v = (t < nw) ? hist[(size_t)t * nbk + b] : 0;
    int sc = v;
    #pragma unroll
    for (int off = 1; off < 64; off <<= 1) {
        int u = __shfl_up(sc, off, 64);
        if (lane >= off) sc += u;
    }
    if (lane == 63) wred[w] = sc;
    __syncthreads();
    if (t == 0) { int a = 0; for (int i = 0; i < 4; ++i) { int xx = wred[i]; wred[i] = a; a += xx; } }
    __syncthreads();
    const int excl = sc - v + wred[w];
    if (t < nw) hist[(size_t)t * nbk + b] = excl;
    if (t == nw - 1) colsum[b] = excl + v;
}

__global__ __launch_bounds__(256) void k_bscan(
    const int* __restrict__ colsum, int* __restrict__ bstart, int nbk, int E)
{
    __shared__ int wred[4];
    const int t = threadIdx.x, lane = t & 63, w = t >> 6;
    const int v = (t < nbk) ? colsum[t] : 0;
    int sc = v;
    #pragma unroll
    for (int off = 1; off < 64; off <<= 1) {
        int u = __shfl_up(sc, off, 64);
        if (lane >= off) sc += u;
    }
    if (lane == 63) wred[w] = sc;
    __syncthreads();
    if (t == 0) { int a = 0; for (int i = 0; i < 4; ++i) { int xx = wred[i]; wred[i] = a; a += xx; } }
    __syncthreads();
    if (t < nbk) bstart[t] = sc - v + wred[w];
    if (t == 0) bstart[nbk] = E;
}

__global__ __launch_bounds__(512) void k_scatter(
    const int* __restrict__ esrc, const int* __restrict__ edst,
    const int* __restrict__ hist, const int* __restrict__ bstart,
    int2* __restrict__ pairs, int E, int nbk)
{
    __shared__ int cur[256];
    const int w = blockIdx.x, t = threadIdx.x;
    for (int i = t; i < nbk; i += 512)
        cur[i] = bstart[i] + hist[(size_t)w * nbk + i];
    __syncthreads();
    const int lo = w * CHUNK, hi = min(E, lo + CHUNK);
    for (int e = lo + 4 * t; e < hi; e += 4 * 512) {
        const int4 s4 = *(const int4*)(esrc + e);
        const int4 d4 = *(const int4*)(edst + e);
        int pos;
        pos = atomicAdd(&cur[d4.x >> BK_SH], 1); pairs[pos] = make_int2(s4.x, d4.x);
        pos = atomicAdd(&cur[d4.y >> BK_SH], 1); pairs[pos] = make_int2(s4.y, d4.y);
        pos = atomicAdd(&cur[d4.z >> BK_SH], 1); pairs[pos] = make_int2(s4.z, d4.z);
        pos = atomicAdd(&cur[d4.w >> BK_SH], 1); pairs[pos] = make_int2(s4.w, d4.w);
    }
}

__global__ __launch_bounds__(512) void k_build(
    const int2* __restrict__ pairs, const int* __restrict__ bstart,
    int* __restrict__ rowptr, int* __restrict__ csr, int n, int nbk)
{
    __shared__ int cnt[512];
    __shared__ int cur[512];
    __shared__ int stage[STAGE];
    __shared__ int wred[8];
    const int b = blockIdx.x, t = threadIdx.x;
    const int base = bstart[b], eend = bstart[b + 1], m = eend - base;
    const int n0 = b << BK_SH;
    const int nn = min(512, n - n0);

    cnt[t] = 0;
    __syncthreads();
    for (int e = base + t; e < eend; e += 512)
        atomicAdd(&cnt[pairs[e].y - n0], 1);
    __syncthreads();

    const int v = cnt[t];
    const int lane = t & 63, w = t >> 6;
    int sc = v;
    #pragma unroll
    for (int off = 1; off < 64; off <<= 1) {
        int u = __shfl_up(sc, off, 64);
        if (lane >= off) sc += u;
    }
    if (lane == 63) wred[w] = sc;
    __syncthreads();
    if (t == 0) { int a = 0; for (int i = 0; i < 8; ++i) { int xx = wred[i]; wred[i] = a; a += xx; } }
    __syncthreads();
    const int excl = sc - v + wred[w];
    cur[t] = excl;
    if (t < nn) rowptr[n0 + t] = base + excl + v;   // inclusive end of node n0+t
    __syncthreads();

    for (int e = base + t; e < eend; e += 512) {
        const int2 p = pairs[e];
        const int loc = atomicAdd(&cur[p.y - n0], 1);
        if (loc < STAGE) stage[loc] = p.x;
        else             csr[base + loc] = p.x;
    }
    __syncthreads();
    const int lim = min(m, STAGE);
    for (int i = t; i < lim; i += 512) csr[base + i] = stage[i];
}

// ---------------------------------------------------------------------------
// Kernel agg1: round-10 version (unchanged — gather engine + BN/ReLU,
// stores h2 fp16).
// ---------------------------------------------------------------------------
__global__ __launch_bounds__(256, 4) void k_agg1(
    const int* __restrict__ csr, const int* __restrict__ rowptr,
    const __half* __restrict__ h1, const float* __restrict__ as1,
    const float* __restrict__ ad1,
    const float* __restrict__ bias1, const float* __restrict__ gamma,
    const float* __restrict__ beta, const float* __restrict__ mean,
    const float* __restrict__ var,
    __half* __restrict__ h2, int n)
{
    __shared__ float sE[16][4][20];        // [group][head][edge]

    const int gi = threadIdx.x >> 4;
    const int q  = threadIdx.x & 15;
    const int myh = q >> 2;
    const unsigned nclamp = (unsigned)(n - 1);

    const float4 b1v = *(const float4*)(bias1 + 4 * q);
    const float4 gmv = *(const float4*)(gamma + 4 * q);
    const float4 vrv = *(const float4*)(var   + 4 * q);
    const float4 mnv = *(const float4*)(mean  + 4 * q);
    const float4 btv = *(const float4*)(beta  + 4 * q);
    float4 scv, shv;
    scv.x = gmv.x * rsqrtf(vrv.x + BN_EPS);
    scv.y = gmv.y * rsqrtf(vrv.y + BN_EPS);
    scv.z = gmv.z * rsqrtf(vrv.z + BN_EPS);
    scv.w = gmv.w * rsqrtf(vrv.w + BN_EPS);
    shv.x = btv.x - mnv.x * scv.x;
    shv.y = btv.y - mnv.y * scv.y;
    shv.z = btv.z - mnv.z * scv.z;
    shv.w = btv.w - mnv.w * scv.w;

    for (int node0 = blockIdx.x * 16; node0 < n; node0 += gridDim.x * 16) {
        const int node = node0 + gi;
        if (node >= n) continue;

        const float4 adv = *(const float4*)(ad1 + node * HEADS);
        const float4 sv4 = *(const float4*)(as1 + node * HEADS);
        float4 eself;
        eself.x = __expf(leaky(sv4.x + adv.x));
        eself.y = __expf(leaky(sv4.y + adv.y));
        eself.z = __expf(leaky(sv4.z + adv.z));
        eself.w = __expf(leaky(sv4.w + adv.w));
        const float es = (myh == 0) ? eself.x : (myh == 1) ? eself.y
                       : (myh == 2) ? eself.z : eself.w;

        float4 acc;
        {
            const half4_t hv = *(const half4_t*)(h1 + (size_t)node * HC + 4 * q);
            acc.x = es * (float)hv[0]; acc.y = es * (float)hv[1];
            acc.z = es * (float)hv[2]; acc.w = es * (float)hv[3];
        }
        float4 dpart = {0.f, 0.f, 0.f, 0.f};

        const int start = (node == 0) ? 0 : rowptr[node - 1];
        const int end   = rowptr[node];

        for (int base = start; base < end; base += 16) {
            const int m = end - base;   // >= 1; may exceed 16
            const int* cb = csr + base;

            // Own-edge index (strided, coalesced) for the score gather.
            const int myraw = cb[min(q, m - 1)];
            // Broadcast loads: all 16 indices in every lane (1-2 lines).
            int idxs[16];
            #pragma unroll
            for (int e = 0; e < 16; ++e) idxs[e] = cb[e];

            // 16 independent clamped gathers, 32-bit offsets.
            half4_t wreg[16];
            #pragma unroll
            for (int e = 0; e < 16; ++e) {
                const unsigned off =
                    (min((unsigned)idxs[e], nclamp) << 7) + ((unsigned)q << 3);
                wreg[e] = *(const half4_t*)((const char*)h1 + off);
            }
            const float4 s4 =
                *(const float4*)(as1 + (size_t)min((unsigned)myraw, nclamp) * HEADS);
            __builtin_amdgcn_sched_barrier(0);   // pin loads before VALU

            const bool val = q < m;
            float4 ea;
            ea.x = val ? __expf(leaky(s4.x + adv.x)) : 0.f;
            ea.y = val ? __expf(leaky(s4.y + adv.y)) : 0.f;
            ea.z = val ? __expf(leaky(s4.z + adv.z)) : 0.f;
            ea.w = val ? __expf(leaky(s4.w + adv.w)) : 0.f;
            dpart.x += ea.x; dpart.y += ea.y;
            dpart.z += ea.z; dpart.w += ea.w;
            sE[gi][0][q] = ea.x;
            sE[gi][1][q] = ea.y;
            sE[gi][2][q] = ea.z;
            sE[gi][3][q] = ea.w;

            float eev[16];
            *(float4*)&eev[0]  = *(const float4*)&sE[gi][myh][0];
            *(float4*)&eev[4]  = *(const float4*)&sE[gi][myh][4];
            *(float4*)&eev[8]  = *(const float4*)&sE[gi][myh][8];
            *(float4*)&eev[12] = *(const float4*)&sE[gi][myh][12];

            #pragma unroll
            for (int e = 0; e < 16; ++e) {
                const float ee = eev[e];
                acc.x = fmaf((float)wreg[e][0], ee, acc.x);
                acc.y = fmaf((float)wreg[e][1], ee, acc.y);
                acc.z = fmaf((float)wreg[e][2], ee, acc.z);
                acc.w = fmaf((float)wreg[e][3], ee, acc.w);
            }
        }

        #pragma unroll
        for (int off = 8; off >= 1; off >>= 1) {
            dpart.x += __shfl_xor(dpart.x, off, 64);
            dpart.y += __shfl_xor(dpart.y, off, 64);
            dpart.z += __shfl_xor(dpart.z, off, 64);
            dpart.w += __shfl_xor(dpart.w, off, 64);
        }
        const float den = es + ((myh == 0) ? dpart.x : (myh == 1) ? dpart.y
                               : (myh == 2) ? dpart.z : dpart.w);
        const float rden = 1.f / den;

        float4 v;
        v.x = fmaxf(fmaf(acc.x * rden + b1v.x, scv.x, shv.x), 0.f);
        v.y = fmaxf(fmaf(acc.y * rden + b1v.y, scv.y, shv.y), 0.f);
        v.z = fmaxf(fmaf(acc.z * rden + b1v.z, scv.z, shv.z), 0.f);
        v.w = fmaxf(fmaf(acc.w * rden + b1v.w, scv.w, shv.w), 0.f);

        half4_t hv2;
        hv2[0] = (_Float16)v.x; hv2[1] = (_Float16)v.y;
        hv2[2] = (_Float16)v.z; hv2[3] = (_Float16)v.w;
        *(half4_t*)(h2 + (size_t)node * HC + 4 * q) = hv2;
    }
}

// ---------------------------------------------------------------------------
// Kernel agg2: round-4/9 pipeline, g at STRIDE 40 (80 B rows).
// Lanes q>=10 read duplicate bytes of the same row (clamped offset):
// branch-free, no extra cache-line traffic, results land in unused lanes.
// ---------------------------------------------------------------------------
__global__ __launch_bounds__(256, 4) void k_agg2(
    const int* __restrict__ csr, const int* __restrict__ rowptr,
    const __half* __restrict__ g, const float* __restrict__ as2,
    const float* __restrict__ ad2, const float* __restrict__ bias2,
    float* __restrict__ out, int n)
{
    __shared__ float sE[16][17];
    __shared__ int   sS[16][17];
    const int gi = threadIdx.x >> 4;
    const int q  = threadIdx.x & 15;
    const unsigned coff = min(8u * (unsigned)q, 72u);   // clamped in-row offset

    float4 b2v = {0.f, 0.f, 0.f, 0.f};
    if (q < 10) b2v = *(const float4*)(bias2 + 4 * q);

    for (int node0 = blockIdx.x * 16; node0 < n; node0 += gridDim.x * 16) {
        const int node = node0 + gi;
        if (node >= n) continue;

        const float ad2d = ad2[node];
        const float eself = __expf(leaky(as2[node] + ad2d));

        float4 acc;
        {
            const half4_t hv =
                *(const half4_t*)((const char*)g + (size_t)node * 80 + coff);
            acc.x = eself * (float)hv[0]; acc.y = eself * (float)hv[1];
            acc.z = eself * (float)hv[2]; acc.w = eself * (float)hv[3];
        }
        float dpart = 0.f;

        const int start = (node == 0) ? 0 : rowptr[node - 1];
        const int end   = rowptr[node];

        if (start < end) {
            int ia = csr[min(start + q, end - 1)];
            for (int base = start; base < end; base += 16) {
                const int m = end - base;

                const float sca = as2[ia];
                const int ia_next = csr[min(base + 16 + q, end - 1)];

                sS[gi][q] = ia;

                int idxs[16];
                #pragma unroll
                for (int e = 0; e < 16; ++e) idxs[e] = sS[gi][e];

                half4_t wreg[16];
                #pragma unroll
                for (int e = 0; e < 16; ++e) {
                    const unsigned off = (unsigned)idxs[e] * 80u + coff;
                    wreg[e] = *(const half4_t*)((const char*)g + off);
                }
                __builtin_amdgcn_sched_barrier(0);   // pin loads before FMAs

                const float ea = (q < m) ? __expf(leaky(sca + ad2d)) : 0.f;
                dpart += ea;
                sE[gi][q] = ea;

                #pragma unroll
                for (int e = 0; e < 16; ++e) {
                    const float ee = sE[gi][e];
                    acc.x = fmaf(ee, (float)wreg[e][0], acc.x);
                    acc.y = fmaf(ee, (float)wreg[e][1], acc.y);
                    acc.z = fmaf(ee, (float)wreg[e][2], acc.z);
                    acc.w = fmaf(ee, (float)wreg[e][3], acc.w);
                }
                ia = ia_next;
            }
        }

        #pragma unroll
        for (int off = 8; off >= 1; off >>= 1)
            dpart += __shfl_xor(dpart, off, 64);
        const float rden = 1.f / (dpart + eself);

        if (q < 10) {
            float4 r;
            r.x = acc.x * rden + b2v.x;
            r.y = acc.y * rden + b2v.y;
            r.z = acc.z * rden + b2v.z;
            r.w = acc.w * rden + b2v.w;
            *(float4*)(out + (size_t)node * NCLASS + 4 * q) = r;
        }
    }
}

extern "C" void kernel_launch(void* const* d_in, const int* in_sizes, int n_in,
                              void* d_out, int out_size, void* d_ws, size_t ws_size,
                              hipStream_t stream)
{
    const float* x    = (const float*)d_in[0];
    const int*   ei   = (const int*)  d_in[1];
    const float* W1   = (const float*)d_in[2];
    const float* as1w = (const float*)d_in[3];
    const float* ad1w = (const float*)d_in[4];
    const float* b1   = (const float*)d_in[5];
    const float* gm   = (const float*)d_in[6];
    const float* bt   = (const float*)d_in[7];
    const float* mn   = (const float*)d_in[8];
    const float* vr   = (const float*)d_in[9];
    const float* W2   = (const float*)d_in[10];
    const float* as2w = (const float*)d_in[11];
    const float* ad2w = (const float*)d_in[12];
    const float* b2   = (const float*)d_in[13];

    const int n = in_sizes[0] / NFEAT;           // 100000
    const int E = in_sizes[1] / 2;               // 1600000
    const int* esrc = ei;
    const int* edst = ei + E;

    const int nbk = (n + 511) >> BK_SH;          // 196 buckets
    const int nw  = (E + CHUNK - 1) / CHUNK;     // 196 chunks

    float*  ws   = (float*)d_ws;
    __half* h1   = (__half*)ws;
    float*  a_s1 = ws   + (size_t)n * 32;
    float*  a_d1 = a_s1 + (size_t)n * 4;
    __half* gbuf = (__half*)(a_d1 + (size_t)n * 4);   // n*40 halves used (stride 40)
    float*  a_s2 = a_d1 + (size_t)n * 4 + (size_t)n * 32;
    float*  a_d2 = a_s2 + n;
    int2*   pairs  = (int2*)(a_d2 + n);
    int*    csr    = (int*)(pairs + E);
    int*    rowptr = csr + E;
    int*    hist   = rowptr + n;
    int*    colsum = hist + (size_t)nw * nbk;
    int*    bstart = colsum + nbk;
    float*  outv = (float*)d_out;

    // pairs (E int2 = 12.8 MB) is dead after k_build; reuse as h2
    // (n x 64 fp16 = 12.8 MB, E == 16n).
    __half* h2buf = (__half*)pairs;

    const int nblk1 = 2048;              // agg1: persistent grid (round 6)
    const int nblk2 = (n + 15) / 16;     // agg2: one block per 16 nodes (round 4)

    k_hist   <<<nw, 512, 0, stream>>>(edst, hist, E, nbk);
    k_colscan<<<nbk, 256, 0, stream>>>(hist, colsum, nbk, nw);
    k_bscan  <<<1, 256, 0, stream>>>(colsum, bstart, nbk, E);
    k_scatter<<<nw, 512, 0, stream>>>(esrc, edst, hist, bstart, pairs, E, nbk);
    k_build  <<<nbk, 512, 0, stream>>>(pairs, bstart, rowptr, csr, n, nbk);
    k_gemm1  <<<512, 256, 0, stream>>>(x, W1, as1w, ad1w, h1, a_s1, a_d1, n);
    k_agg1   <<<nblk1, 256, 0, stream>>>(csr, rowptr, h1, a_s1, a_d1,
                                         b1, gm, bt, mn, vr, h2buf, n);
    k_gemm2  <<<512, 256, 0, stream>>>(h2buf, W2, as2w, ad2w,
                                       gbuf, a_s2, a_d2, n);
    k_agg2   <<<nblk2, 256, 0, stream>>>(csr, rowptr, gbuf, a_s2, a_d2,
                                         b2, outv, n);
}

// Round 12
// 249.785 us; speedup vs baseline: 1.0130x; 1.0130x over previous
//
#include <hip/hip_runtime.h>
#include <hip/hip_bf16.h>
#include <hip/hip_fp16.h>

#define NFEAT  128
#define HC     64
#define HEADS  4
#define NHID   16
#define NCLASS 40
#define NEG    0.2f
#define BN_EPS 1e-5f

#define BK_SH   9          // 512 nodes per bucket
#define CHUNK   8192       // edges per histogram/scatter workgroup
#define STAGE   12288      // LDS staging capacity in k_build

typedef _Float16 half8_t __attribute__((ext_vector_type(8)));
typedef _Float16 half4_t __attribute__((ext_vector_type(4)));
typedef float    f32x4_t __attribute__((ext_vector_type(4)));

__device__ __forceinline__ float leaky(float a) { return (a > 0.f) ? a : NEG * a; }

// ---------------------------------------------------------------------------
// Kernel 1 (MFMA): h1 = x @ W1 via v_mfma_f32_16x16x32_f16.
// ---------------------------------------------------------------------------
__global__ __launch_bounds__(256) void k_gemm1(
    const float* __restrict__ x, const float* __restrict__ W1,
    const float* __restrict__ att_s, const float* __restrict__ att_d,
    __half* __restrict__ h1, float* __restrict__ as1, float* __restrict__ ad1,
    int n)
{
    const int wave = threadIdx.x >> 6, lane = threadIdx.x & 63;
    const int quad = lane >> 4, l16 = lane & 15;

    half8_t bfrag[4][4];
    #pragma unroll
    for (int ks = 0; ks < 4; ++ks)
        #pragma unroll
        for (int ct = 0; ct < 4; ++ct)
            #pragma unroll
            for (int j = 0; j < 8; ++j)
                bfrag[ks][ct][j] =
                    (_Float16)W1[(ks * 32 + quad * 8 + j) * HC + ct * 16 + l16];

    float avs[4], avd[4];
    #pragma unroll
    for (int ct = 0; ct < 4; ++ct) {
        avs[ct] = att_s[ct * 16 + l16];
        avd[ct] = att_d[ct * 16 + l16];
    }

    const int nslab = (n + 15) >> 4;
    for (int slab = blockIdx.x * 4 + wave; slab < nslab; slab += gridDim.x * 4) {
        const int rowbase = slab * 16;
        const int arow = min(rowbase + l16, n - 1);
        const float* xp = x + (size_t)arow * NFEAT;

        f32x4_t acc[4] = {{0.f,0.f,0.f,0.f},{0.f,0.f,0.f,0.f},
                          {0.f,0.f,0.f,0.f},{0.f,0.f,0.f,0.f}};
        #pragma unroll
        for (int ks = 0; ks < 4; ++ks) {
            const float4 xa = *(const float4*)(xp + ks * 32 + quad * 8);
            const float4 xb = *(const float4*)(xp + ks * 32 + quad * 8 + 4);
            half8_t af;
            af[0] = (_Float16)xa.x; af[1] = (_Float16)xa.y;
            af[2] = (_Float16)xa.z; af[3] = (_Float16)xa.w;
            af[4] = (_Float16)xb.x; af[5] = (_Float16)xb.y;
            af[6] = (_Float16)xb.z; af[7] = (_Float16)xb.w;
            #pragma unroll
            for (int ct = 0; ct < 4; ++ct)
                acc[ct] = __builtin_amdgcn_mfma_f32_16x16x32_f16(
                    af, bfrag[ks][ct], acc[ct], 0, 0, 0);
        }

        #pragma unroll
        for (int reg = 0; reg < 4; ++reg) {
            const int row = rowbase + quad * 4 + reg;
            const bool valid = row < n;

            float4 ps, pd;
            ps.x = acc[0][reg] * avs[0]; pd.x = acc[0][reg] * avd[0];
            ps.y = acc[1][reg] * avs[1]; pd.y = acc[1][reg] * avd[1];
            ps.z = acc[2][reg] * avs[2]; pd.z = acc[2][reg] * avd[2];
            ps.w = acc[3][reg] * avs[3]; pd.w = acc[3][reg] * avd[3];
            #pragma unroll
            for (int off = 8; off >= 1; off >>= 1) {
                ps.x += __shfl_xor(ps.x, off, 64); pd.x += __shfl_xor(pd.x, off, 64);
                ps.y += __shfl_xor(ps.y, off, 64); pd.y += __shfl_xor(pd.y, off, 64);
                ps.z += __shfl_xor(ps.z, off, 64); pd.z += __shfl_xor(pd.z, off, 64);
                ps.w += __shfl_xor(ps.w, off, 64); pd.w += __shfl_xor(pd.w, off, 64);
            }
            if (valid) {
                #pragma unroll
                for (int ct = 0; ct < 4; ++ct)
                    h1[(size_t)row * HC + ct * 16 + l16] =
                        __float2half_rn(acc[ct][reg]);
                if (l16 == 0) {
                    *(float4*)(as1 + (size_t)row * HEADS) = ps;
                    *(float4*)(ad1 + (size_t)row * HEADS) = pd;
                }
            }
        }
    }
}

// ---------------------------------------------------------------------------
// Kernel gemm2 (MFMA): g = h2 @ W2 (64 -> 40, padded to 64 cols, cols>=40
// zeroed) + layer-2 attention scores as2/ad2. Sibling of k_gemm1.
// ---------------------------------------------------------------------------
__global__ __launch_bounds__(256) void k_gemm2(
    const __half* __restrict__ h2, const float* __restrict__ W2,
    const float* __restrict__ ats2, const float* __restrict__ atd2,
    __half* __restrict__ g, float* __restrict__ as2, float* __restrict__ ad2,
    int n)
{
    const int wave = threadIdx.x >> 6, lane = threadIdx.x & 63;
    const int quad = lane >> 4, l16 = lane & 15;

    half8_t bfrag[2][3];
    #pragma unroll
    for (int ks = 0; ks < 2; ++ks)
        #pragma unroll
        for (int ct = 0; ct < 3; ++ct)
            #pragma unroll
            for (int j = 0; j < 8; ++j) {
                const int c = ct * 16 + l16;
                bfrag[ks][ct][j] = (c < NCLASS)
                    ? (_Float16)W2[(ks * 32 + quad * 8 + j) * NCLASS + c]
                    : (_Float16)0.f;
            }

    float avs[3], avd[3];
    #pragma unroll
    for (int ct = 0; ct < 3; ++ct) {
        const int c = ct * 16 + l16;
        avs[ct] = (c < NCLASS) ? ats2[c] : 0.f;
        avd[ct] = (c < NCLASS) ? atd2[c] : 0.f;
    }

    const int nslab = (n + 15) >> 4;
    for (int slab = blockIdx.x * 4 + wave; slab < nslab; slab += gridDim.x * 4) {
        const int rowbase = slab * 16;
        const int arow = min(rowbase + l16, n - 1);
        const __half* hp = h2 + (size_t)arow * HC;

        f32x4_t acc[3] = {{0.f,0.f,0.f,0.f},{0.f,0.f,0.f,0.f},
                          {0.f,0.f,0.f,0.f}};
        #pragma unroll
        for (int ks = 0; ks < 2; ++ks) {
            const half8_t af = *(const half8_t*)(hp + ks * 32 + quad * 8);
            #pragma unroll
            for (int ct = 0; ct < 3; ++ct)
                acc[ct] = __builtin_amdgcn_mfma_f32_16x16x32_f16(
                    af, bfrag[ks][ct], acc[ct], 0, 0, 0);
        }

        #pragma unroll
        for (int reg = 0; reg < 4; ++reg) {
            const int row = rowbase + quad * 4 + reg;
            const bool valid = row < n;

            float sv = acc[0][reg] * avs[0] + acc[1][reg] * avs[1]
                     + acc[2][reg] * avs[2];
            float dv = acc[0][reg] * avd[0] + acc[1][reg] * avd[1]
                     + acc[2][reg] * avd[2];
            #pragma unroll
            for (int off = 8; off >= 1; off >>= 1) {
                sv += __shfl_xor(sv, off, 64);
                dv += __shfl_xor(dv, off, 64);
            }
            if (valid) {
                #pragma unroll
                for (int ct = 0; ct < 3; ++ct)
                    g[(size_t)row * HC + ct * 16 + l16] =
                        __float2half_rn(acc[ct][reg]);
                g[(size_t)row * HC + 48 + l16] = __float2half_rn(0.f);
                if (l16 == 0) { as2[row] = sv; ad2[row] = dv; }
            }
        }
    }
}

// ---------------------------------------------------------------------------
// CSR build (locality-preserving, no global atomics, no memset)
// ---------------------------------------------------------------------------
__global__ __launch_bounds__(512) void k_hist(
    const int* __restrict__ edst, int* __restrict__ hist, int E, int nbk)
{
    __shared__ int lh[256];
    const int w = blockIdx.x, t = threadIdx.x;
    for (int i = t; i < nbk; i += 512) lh[i] = 0;
    __syncthreads();
    const int lo = w * CHUNK, hi = min(E, lo + CHUNK);
    for (int e = lo + 4 * t; e < hi; e += 4 * 512) {
        const int4 d4 = *(const int4*)(edst + e);
        atomicAdd(&lh[d4.x >> BK_SH], 1);
        atomicAdd(&lh[d4.y >> BK_SH], 1);
        atomicAdd(&lh[d4.z >> BK_SH], 1);
        atomicAdd(&lh[d4.w >> BK_SH], 1);
    }
    __syncthreads();
    for (int i = t; i < nbk; i += 512) hist[(size_t)w * nbk + i] = lh[i];
}

__global__ __launch_bounds__(256) void k_colscan(
    int* __restrict__ hist, int* __restrict__ colsum, int nbk, int nw)
{
    __shared__ int wred[4];
    const int b = blockIdx.x, t = threadIdx.x;
    const int lane = t & 63, w = t >> 6;
    const int v = (t < nw) ? hist[(size_t)t * nbk + b] : 0;
    int sc = v;
    #pragma unroll
    for (int off = 1; off < 64; off <<= 1) {
        int u = __shfl_up(sc, off, 64);
        if (lane >= off) sc += u;
    }
    if (lane == 63) wred[w] = sc;
    __syncthreads();
    if (t == 0) { int a = 0; for (int i = 0; i < 4; ++i) { int xx = wred[i]; wred[i] = a; a += xx; } }
    __syncthreads();
    const int excl = sc - v + wred[w];
    if (t < nw) hist[(size_t)t * nbk + b] = excl;
    if (t == nw - 1) colsum[b] = excl + v;
}

__global__ __launch_bounds__(256) void k_bscan(
    const int* __restrict__ colsum, int* __restrict__ bstart, int nbk, int E)
{
    __shared__ int wred[4];
    const int t = threadIdx.x, lane = t & 63, w = t >> 6;
    const int v = (t < nbk) ? colsum[t] : 0;
    int sc = v;
    #pragma unroll
    for (int off = 1; off < 64; off <<= 1) {
        int u = __shfl_up(sc, off, 64);
        if (lane >= off) sc += u;
    }
    if (lane == 63) wred[w] = sc;
    __syncthreads();
    if (t == 0) { int a = 0; for (int i = 0; i < 4; ++i) { int xx = wred[i]; wred[i] = a; a += xx; } }
    __syncthreads();
    if (t < nbk) bstart[t] = sc - v + wred[w];
    if (t == 0) bstart[nbk] = E;
}

__global__ __launch_bounds__(512) void k_scatter(
    const int* __restrict__ esrc, const int* __restrict__ edst,
    const int* __restrict__ hist, const int* __restrict__ bstart,
    int2* __restrict__ pairs, int E, int nbk)
{
    __shared__ int cur[256];
    const int w = blockIdx.x, t = threadIdx.x;
    for (int i = t; i < nbk; i += 512)
        cur[i] = bstart[i] + hist[(size_t)w * nbk + i];
    __syncthreads();
    const int lo = w * CHUNK, hi = min(E, lo + CHUNK);
    for (int e = lo + 4 * t; e < hi; e += 4 * 512) {
        const int4 s4 = *(const int4*)(esrc + e);
        const int4 d4 = *(const int4*)(edst + e);
        int pos;
        pos = atomicAdd(&cur[d4.x >> BK_SH], 1); pairs[pos] = make_int2(s4.x, d4.x);
        pos = atomicAdd(&cur[d4.y >> BK_SH], 1); pairs[pos] = make_int2(s4.y, d4.y);
        pos = atomicAdd(&cur[d4.z >> BK_SH], 1); pairs[pos] = make_int2(s4.z, d4.z);
        pos = atomicAdd(&cur[d4.w >> BK_SH], 1); pairs[pos] = make_int2(s4.w, d4.w);
    }
}

__global__ __launch_bounds__(512) void k_build(
    const int2* __restrict__ pairs, const int* __restrict__ bstart,
    int* __restrict__ rowptr, int* __restrict__ csr, int n, int nbk)
{
    __shared__ int cnt[512];
    __shared__ int cur[512];
    __shared__ int stage[STAGE];
    __shared__ int wred[8];
    const int b = blockIdx.x, t = threadIdx.x;
    const int base = bstart[b], eend = bstart[b + 1], m = eend - base;
    const int n0 = b << BK_SH;
    const int nn = min(512, n - n0);

    cnt[t] = 0;
    __syncthreads();
    for (int e = base + t; e < eend; e += 512)
        atomicAdd(&cnt[pairs[e].y - n0], 1);
    __syncthreads();

    const int v = cnt[t];
    const int lane = t & 63, w = t >> 6;
    int sc = v;
    #pragma unroll
    for (int off = 1; off < 64; off <<= 1) {
        int u = __shfl_up(sc, off, 64);
        if (lane >= off) sc += u;
    }
    if (lane == 63) wred[w] = sc;
    __syncthreads();
    if (t == 0) { int a = 0; for (int i = 0; i < 8; ++i) { int xx = wred[i]; wred[i] = a; a += xx; } }
    __syncthreads();
    const int excl = sc - v + wred[w];
    cur[t] = excl;
    if (t < nn) rowptr[n0 + t] = base + excl + v;   // inclusive end of node n0+t
    __syncthreads();

    for (int e = base + t; e < eend; e += 512) {
        const int2 p = pairs[e];
        const int loc = atomicAdd(&cur[p.y - n0], 1);
        if (loc < STAGE) stage[loc] = p.x;
        else             csr[base + loc] = p.x;
    }
    __syncthreads();
    const int lim = min(m, STAGE);
    for (int i = t; i < lim; i += 512) csr[base + i] = stage[i];
}

// ---------------------------------------------------------------------------
// Kernel agg1: gather engine + BN/ReLU, stores h2 fp16 (round-10 version).
// ---------------------------------------------------------------------------
__global__ __launch_bounds__(256, 4) void k_agg1(
    const int* __restrict__ csr, const int* __restrict__ rowptr,
    const __half* __restrict__ h1, const float* __restrict__ as1,
    const float* __restrict__ ad1,
    const float* __restrict__ bias1, const float* __restrict__ gamma,
    const float* __restrict__ beta, const float* __restrict__ mean,
    const float* __restrict__ var,
    __half* __restrict__ h2, int n)
{
    __shared__ float sE[16][4][20];        // [group][head][edge]

    const int gi = threadIdx.x >> 4;
    const int q  = threadIdx.x & 15;
    const int myh = q >> 2;
    const unsigned nclamp = (unsigned)(n - 1);

    const float4 b1v = *(const float4*)(bias1 + 4 * q);
    const float4 gmv = *(const float4*)(gamma + 4 * q);
    const float4 vrv = *(const float4*)(var   + 4 * q);
    const float4 mnv = *(const float4*)(mean  + 4 * q);
    const float4 btv = *(const float4*)(beta  + 4 * q);
    float4 scv, shv;
    scv.x = gmv.x * rsqrtf(vrv.x + BN_EPS);
    scv.y = gmv.y * rsqrtf(vrv.y + BN_EPS);
    scv.z = gmv.z * rsqrtf(vrv.z + BN_EPS);
    scv.w = gmv.w * rsqrtf(vrv.w + BN_EPS);
    shv.x = btv.x - mnv.x * scv.x;
    shv.y = btv.y - mnv.y * scv.y;
    shv.z = btv.z - mnv.z * scv.z;
    shv.w = btv.w - mnv.w * scv.w;

    for (int node0 = blockIdx.x * 16; node0 < n; node0 += gridDim.x * 16) {
        const int node = node0 + gi;
        if (node >= n) continue;

        const float4 adv = *(const float4*)(ad1 + node * HEADS);
        const float4 sv4 = *(const float4*)(as1 + node * HEADS);
        float4 eself;
        eself.x = __expf(leaky(sv4.x + adv.x));
        eself.y = __expf(leaky(sv4.y + adv.y));
        eself.z = __expf(leaky(sv4.z + adv.z));
        eself.w = __expf(leaky(sv4.w + adv.w));
        const float es = (myh == 0) ? eself.x : (myh == 1) ? eself.y
                       : (myh == 2) ? eself.z : eself.w;

        float4 acc;
        {
            const half4_t hv = *(const half4_t*)(h1 + (size_t)node * HC + 4 * q);
            acc.x = es * (float)hv[0]; acc.y = es * (float)hv[1];
            acc.z = es * (float)hv[2]; acc.w = es * (float)hv[3];
        }
        float4 dpart = {0.f, 0.f, 0.f, 0.f};

        const int start = (node == 0) ? 0 : rowptr[node - 1];
        const int end   = rowptr[node];

        for (int base = start; base < end; base += 16) {
            const int m = end - base;   // >= 1; may exceed 16
            const int* cb = csr + base;

            // Own-edge index (strided, coalesced) for the score gather.
            const int myraw = cb[min(q, m - 1)];
            // Broadcast loads: all 16 indices in every lane (1-2 lines).
            int idxs[16];
            #pragma unroll
            for (int e = 0; e < 16; ++e) idxs[e] = cb[e];

            // 16 independent clamped gathers, 32-bit offsets.
            half4_t wreg[16];
            #pragma unroll
            for (int e = 0; e < 16; ++e) {
                const unsigned off =
                    (min((unsigned)idxs[e], nclamp) << 7) + ((unsigned)q << 3);
                wreg[e] = *(const half4_t*)((const char*)h1 + off);
            }
            const float4 s4 =
                *(const float4*)(as1 + (size_t)min((unsigned)myraw, nclamp) * HEADS);
            __builtin_amdgcn_sched_barrier(0);   // pin loads before VALU

            const bool val = q < m;
            float4 ea;
            ea.x = val ? __expf(leaky(s4.x + adv.x)) : 0.f;
            ea.y = val ? __expf(leaky(s4.y + adv.y)) : 0.f;
            ea.z = val ? __expf(leaky(s4.z + adv.z)) : 0.f;
            ea.w = val ? __expf(leaky(s4.w + adv.w)) : 0.f;
            dpart.x += ea.x; dpart.y += ea.y;
            dpart.z += ea.z; dpart.w += ea.w;
            sE[gi][0][q] = ea.x;
            sE[gi][1][q] = ea.y;
            sE[gi][2][q] = ea.z;
            sE[gi][3][q] = ea.w;

            float eev[16];
            *(float4*)&eev[0]  = *(const float4*)&sE[gi][myh][0];
            *(float4*)&eev[4]  = *(const float4*)&sE[gi][myh][4];
            *(float4*)&eev[8]  = *(const float4*)&sE[gi][myh][8];
            *(float4*)&eev[12] = *(const float4*)&sE[gi][myh][12];

            #pragma unroll
            for (int e = 0; e < 16; ++e) {
                const float ee = eev[e];
                acc.x = fmaf((float)wreg[e][0], ee, acc.x);
                acc.y = fmaf((float)wreg[e][1], ee, acc.y);
                acc.z = fmaf((float)wreg[e][2], ee, acc.z);
                acc.w = fmaf((float)wreg[e][3], ee, acc.w);
            }
        }

        #pragma unroll
        for (int off = 8; off >= 1; off >>= 1) {
            dpart.x += __shfl_xor(dpart.x, off, 64);
            dpart.y += __shfl_xor(dpart.y, off, 64);
            dpart.z += __shfl_xor(dpart.z, off, 64);
            dpart.w += __shfl_xor(dpart.w, off, 64);
        }
        const float den = es + ((myh == 0) ? dpart.x : (myh == 1) ? dpart.y
                               : (myh == 2) ? dpart.z : dpart.w);
        const float rden = 1.f / den;

        float4 v;
        v.x = fmaxf(fmaf(acc.x * rden + b1v.x, scv.x, shv.x), 0.f);
        v.y = fmaxf(fmaf(acc.y * rden + b1v.y, scv.y, shv.y), 0.f);
        v.z = fmaxf(fmaf(acc.z * rden + b1v.z, scv.z, shv.z), 0.f);
        v.w = fmaxf(fmaf(acc.w * rden + b1v.w, scv.w, shv.w), 0.f);

        half4_t hv2;
        hv2[0] = (_Float16)v.x; hv2[1] = (_Float16)v.y;
        hv2[2] = (_Float16)v.z; hv2[3] = (_Float16)v.w;
        *(half4_t*)(h2 + (size_t)node * HC + 4 * q) = hv2;
    }
}

// ---------------------------------------------------------------------------
// Kernel agg2: round-4/9/10 version (g at stride 64, 128 B-aligned rows).
// ---------------------------------------------------------------------------
__global__ __launch_bounds__(256, 4) void k_agg2(
    const int* __restrict__ csr, const int* __restrict__ rowptr,
    const __half* __restrict__ g, const float* __restrict__ as2,
    const float* __restrict__ ad2, const float* __restrict__ bias2,
    float* __restrict__ out, int n)
{
    __shared__ float sE[16][17];
    __shared__ int   sS[16][17];
    const int gi = threadIdx.x >> 4;
    const int q  = threadIdx.x & 15;

    float4 b2v = {0.f, 0.f, 0.f, 0.f};
    if (q < 10) b2v = *(const float4*)(bias2 + 4 * q);

    for (int node0 = blockIdx.x * 16; node0 < n; node0 += gridDim.x * 16) {
        const int node = node0 + gi;
        if (node >= n) continue;

        const float ad2d = ad2[node];
        const float eself = __expf(leaky(as2[node] + ad2d));

        float2 raws = *(const float2*)(g + (size_t)node * HC + 4 * q);
        const float2 s0v = __half22float2(*(__half2*)&raws.x);
        const float2 s1v = __half22float2(*(__half2*)&raws.y);
        float4 acc;
        acc.x = eself * s0v.x; acc.y = eself * s0v.y;
        acc.z = eself * s1v.x; acc.w = eself * s1v.y;
        float dpart = 0.f;

        const int start = (node == 0) ? 0 : rowptr[node - 1];
        const int end   = rowptr[node];

        if (start < end) {
            int ia = csr[min(start + q, end - 1)];
            for (int base = start; base < end; base += 16) {
                const int m = end - base;

                const float sca = as2[ia];
                const int ia_next = csr[min(base + 16 + q, end - 1)];

                sS[gi][q] = ia;

                int idxs[16];
                #pragma unroll
                for (int e = 0; e < 16; ++e) idxs[e] = sS[gi][e];

                float2 wreg[16];
                #pragma unroll
                for (int e = 0; e < 16; ++e)
                    wreg[e] = *(const float2*)(g + (size_t)idxs[e] * HC + 4 * q);
                __builtin_amdgcn_sched_barrier(0);   // pin loads before FMAs

                const float ea = (q < m) ? __expf(leaky(sca + ad2d)) : 0.f;
                dpart += ea;
                sE[gi][q] = ea;

                #pragma unroll
                for (int e = 0; e < 16; ++e) {
                    const float ee = sE[gi][e];
                    const float2 a0 = __half22float2(*(const __half2*)&wreg[e].x);
                    const float2 a1 = __half22float2(*(const __half2*)&wreg[e].y);
                    acc.x = fmaf(ee, a0.x, acc.x); acc.y = fmaf(ee, a0.y, acc.y);
                    acc.z = fmaf(ee, a1.x, acc.z); acc.w = fmaf(ee, a1.y, acc.w);
                }
                ia = ia_next;
            }
        }

        #pragma unroll
        for (int off = 8; off >= 1; off >>= 1)
            dpart += __shfl_xor(dpart, off, 64);
        const float rden = 1.f / (dpart + eself);

        if (q < 10) {
            float4 r;
            r.x = acc.x * rden + b2v.x;
            r.y = acc.y * rden + b2v.y;
            r.z = acc.z * rden + b2v.z;
            r.w = acc.w * rden + b2v.w;
            *(float4*)(out + (size_t)node * NCLASS + 4 * q) = r;
        }
    }
}

extern "C" void kernel_launch(void* const* d_in, const int* in_sizes, int n_in,
                              void* d_out, int out_size, void* d_ws, size_t ws_size,
                              hipStream_t stream)
{
    const float* x    = (const float*)d_in[0];
    const int*   ei   = (const int*)  d_in[1];
    const float* W1   = (const float*)d_in[2];
    const float* as1w = (const float*)d_in[3];
    const float* ad1w = (const float*)d_in[4];
    const float* b1   = (const float*)d_in[5];
    const float* gm   = (const float*)d_in[6];
    const float* bt   = (const float*)d_in[7];
    const float* mn   = (const float*)d_in[8];
    const float* vr   = (const float*)d_in[9];
    const float* W2   = (const float*)d_in[10];
    const float* as2w = (const float*)d_in[11];
    const float* ad2w = (const float*)d_in[12];
    const float* b2   = (const float*)d_in[13];

    const int n = in_sizes[0] / NFEAT;           // 100000
    const int E = in_sizes[1] / 2;               // 1600000
    const int* esrc = ei;
    const int* edst = ei + E;

    const int nbk = (n + 511) >> BK_SH;          // 196 buckets
    const int nw  = (E + CHUNK - 1) / CHUNK;     // 196 chunks

    float*  ws   = (float*)d_ws;
    __half* h1   = (__half*)ws;
    float*  a_s1 = ws   + (size_t)n * 32;
    float*  a_d1 = a_s1 + (size_t)n * 4;
    __half* gbuf = (__half*)(a_d1 + (size_t)n * 4);
    float*  a_s2 = a_d1 + (size_t)n * 4 + (size_t)n * 32;
    float*  a_d2 = a_s2 + n;
    int2*   pairs  = (int2*)(a_d2 + n);
    int*    csr    = (int*)(pairs + E);
    int*    rowptr = csr + E;
    int*    hist   = rowptr + n;
    int*    colsum = hist + (size_t)nw * nbk;
    int*    bstart = colsum + nbk;
    float*  outv = (float*)d_out;

    // pairs (E int2 = 12.8 MB) is dead after k_build; reuse as h2
    // (n x 64 fp16 = 12.8 MB, E == 16n).
    __half* h2buf = (__half*)pairs;

    const int nblk1 = 2048;              // agg1: persistent grid (round 6)
    const int nblk2 = (n + 15) / 16;     // agg2: one block per 16 nodes (round 4)

    k_hist   <<<nw, 512, 0, stream>>>(edst, hist, E, nbk);
    k_colscan<<<nbk, 256, 0, stream>>>(hist, colsum, nbk, nw);
    k_bscan  <<<1, 256, 0, stream>>>(colsum, bstart, nbk, E);
    k_scatter<<<nw, 512, 0, stream>>>(esrc, edst, hist, bstart, pairs, E, nbk);
    k_build  <<<nbk, 512, 0, stream>>>(pairs, bstart, rowptr, csr, n, nbk);
    k_gemm1  <<<512, 256, 0, stream>>>(x, W1, as1w, ad1w, h1, a_s1, a_d1, n);
    k_agg1   <<<nblk1, 256, 0, stream>>>(csr, rowptr, h1, a_s1, a_d1,
                                         b1, gm, bt, mn, vr, h2buf, n);
    k_gemm2  <<<512, 256, 0, stream>>>(h2buf, W2, as2w, ad2w,
                                       gbuf, a_s2, a_d2, n);
    k_agg2   <<<nblk2, 256, 0, stream>>>(csr, rowptr, gbuf, a_s2, a_d2,
                                         b2, outv, n);
}